// Round 8
// baseline (261.996 us; speedup 1.0000x reference)
//
#include <hip/hip_runtime.h>

#define BATCH 4
#define CIN 1024
#define T 512
#define HW 49
#define C 2048
#define D 128
#define L 101
#define HALF 50
#define OUTD 128

#if defined(__has_builtin)
#if __has_builtin(__builtin_amdgcn_global_load_lds)
#define HAS_GLLDS 1
#endif
#endif

typedef float f32x4 __attribute__((ext_vector_type(4)));

__device__ __forceinline__ void gl2lds16(const float4* g, float4* l) {
#ifdef HAS_GLLDS
    __builtin_amdgcn_global_load_lds(
        (const __attribute__((address_space(1))) void*)g,
        (__attribute__((address_space(3))) void*)l, 16, 0, 0);
#else
    *l = *g;   // host-pass placeholder; device always takes HAS_GLLDS
#endif
}

__device__ __forceinline__ f32x4 ntload4(const f32x4* p) {
    return __builtin_nontemporal_load(p);
}

// ---------------------------------------------------------------------------
// meanprep: blocks [0,8192) = spatial mean; blocks [8192,8499) = weight prep.
//
// Mean path: 4 chunks of 128 rows, VGPR-staged (plain NT loads -> regs ->
// ds_write), register ping-pong ra/rb, ONE raw s_barrier per chunk.
// Compiler inserts minimal per-reg vmcnt before the ds_writes, so prefetched
// next-chunk loads stay in flight across the barrier (no vmcnt(0) drain).
// Tests whether the global_load_lds DMA path was capping read BW.
// ---------------------------------------------------------------------------
__global__ __launch_bounds__(256) void meanprep_kernel(const float* __restrict__ x1,
                                                       const float* __restrict__ x2,
                                                       float* __restrict__ feats,
                                                       const float* __restrict__ Wp,
                                                       const float* __restrict__ Wf,
                                                       float* __restrict__ WpT,
                                                       float* __restrict__ WfT) {
    __shared__ __align__(16) float4 buf[2][1568];        // 2 x 25088 B
    int tid = threadIdx.x;

    if (blockIdx.x >= 8192) {
        // ------------------- prep path (LDS aliased onto buf) -------------------
        float* tile = reinterpret_cast<float*>(buf);     // [32][33]
        int bid2 = blockIdx.x - 8192;
        if (bid2 < 256) {
            int ct = bid2 & 63, dt = bid2 >> 6;
            int c0 = ct * 32, d0 = dt * 32;
            int col = tid & 31, row = tid >> 5;
#pragma unroll
            for (int i = 0; i < 4; ++i) {
                int dl = row + i * 8;
                tile[dl * 33 + col] = Wp[(long long)(d0 + dl) * C + c0 + col];
            }
            __syncthreads();
#pragma unroll
            for (int i = 0; i < 4; ++i) {
                int cc = row + i * 8;
                WpT[(long long)(c0 + cc) * D + d0 + col] = tile[col * 33 + cc];
            }
        } else {
            int idx = (bid2 - 256) * 256 + tid;
            if (idx < L * OUTD) {
                int l = idx >> 7, o = idx & 127;
                WfT[idx] = Wf[o * L + l];
            }
        }
        return;
    }

    // --------------------------- mean path ---------------------------
    const long long Mrows = (long long)BATCH * CIN * T;  // 2097152 per input
    long long row0 = (long long)blockIdx.x * 512;        // 4 chunks x 128 rows
    const float* src;
    long long m0;
    int half;
    if (row0 < Mrows) { src = x1; m0 = row0; half = 0; }
    else              { src = x2; m0 = row0 - Mrows; half = 1; }

    const f32x4* src4 = reinterpret_cast<const f32x4*>(src) + (((long long)m0 * HW) >> 2);
    int w    = tid >> 6;      // wave id 0..3
    int lane = tid & 63;
    const int wofs = w * 392;  // per-chunk float4 span 1568; per wave 392 = 6*64+8
    int r = tid >> 1, p = tid & 1;

    f32x4 ra[7], rb[7];

    auto loadc = [&](f32x4* rr, int ck) {
        const f32x4* gb = src4 + (long long)ck * 1568 + wofs;
#pragma unroll
        for (int k = 0; k < 6; ++k)
            rr[k] = ntload4(gb + k * 64 + lane);
        if (lane < 8)
            rr[6] = ntload4(gb + 384 + lane);
    };
    auto writec = [&](const f32x4* rr, int ck) {
        f32x4* lb = reinterpret_cast<f32x4*>(buf[ck & 1]) + wofs;
#pragma unroll
        for (int k = 0; k < 6; ++k)
            lb[k * 64 + lane] = rr[k];
        if (lane < 8)
            lb[384 + lane] = rr[6];
    };
    auto reduce = [&](int ck) {
        const float* base = reinterpret_cast<const float*>(buf[ck & 1]);
        const float* rowp = base + r * HW + p * 24;
        float s0 = 0.f, s1 = 0.f, s2 = 0.f, s3 = 0.f;
#pragma unroll
        for (int j = 0; j < 6; ++j) {
            s0 += rowp[j];
            s1 += rowp[6 + j];
            s2 += rowp[12 + j];
            s3 += rowp[18 + j];
        }
        float s = (s0 + s1) + (s2 + s3);
        if (p == 0) s += base[r * HW + 48];
        s += __shfl_xor(s, 1);
        if (p == 0) {
            long long m = m0 + (long long)ck * 128 + r;
            long long b = m >> 19;                 // / (1024*512)
            long long rem = m & ((1LL << 19) - 1); // c*512 + t
            feats[(b << 20) + ((long long)half << 19) + rem] = s * (1.0f / 49.0f);
        }
    };
    auto stepbar = [&]() {
        asm volatile("s_waitcnt lgkmcnt(0)" ::: "memory");
        __builtin_amdgcn_s_barrier();
        __builtin_amdgcn_sched_barrier(0);
    };

    loadc(ra, 0);
    __builtin_amdgcn_sched_barrier(0);

    loadc(rb, 1); __builtin_amdgcn_sched_barrier(0); writec(ra, 0); stepbar(); reduce(0);
    loadc(ra, 2); __builtin_amdgcn_sched_barrier(0); writec(rb, 1); stepbar(); reduce(1);
    loadc(rb, 3); __builtin_amdgcn_sched_barrier(0); writec(ra, 2); stepbar(); reduce(2);
    writec(rb, 3); stepbar(); reduce(3);
}

// ---------------------------------------------------------------------------
// projnorm: full-K projection + fused L2 normalize -> xn[b*T+t][d].
// grid = 4(b) x 64(t-tile of 8) = 256 blocks, 256 threads (dg 32 x tg 8).
// 8 kc-chunks of 256 c, double-buffered glds staging, counted vmcnt(2),
// two raw barriers per chunk (same verified pattern as rounds 4-7 mean).
// Epilogue: per-t sum of squares via 5-level shfl_xor within 32-lane group.
// ---------------------------------------------------------------------------
__global__ __launch_bounds__(256) void projnorm_kernel(const float* __restrict__ feats,
                                                       const float* __restrict__ WpT,
                                                       float* __restrict__ xn) {
    int bid = blockIdx.x;
    int b  = bid >> 6;
    int tt = bid & 63;
    int t0 = tt * 8;

    __shared__ __align__(16) float fl[2][256 * 8];   // 2 x 8 KB
    int tid = threadIdx.x;
    int dg = tid & 31, tg = tid >> 5;

    const float4* feats4 = reinterpret_cast<const float4*>(feats);
    auto issue = [&](int kc) {
#pragma unroll
        for (int i = 0; i < 2; ++i) {
            int s = i * 256 + tid;           // 512 float4 per chunk
            int c = s >> 1, tq = s & 1;      // 8 floats per c-row = 2 float4
            gl2lds16(feats4 + (((long long)(b * C + kc * 256 + c)) << 7) + (t0 >> 2) + tq,
                     reinterpret_cast<float4*>(fl[kc & 1]) + s);
        }
    };

    issue(0);
    float4 acc = make_float4(0.f, 0.f, 0.f, 0.f);
    const float4* WpT4 = reinterpret_cast<const float4*>(WpT);

    for (int kc = 0; kc < 8; ++kc) {
        if (kc < 7) {
            issue(kc + 1);
            asm volatile("s_waitcnt vmcnt(2)" ::: "memory");
        } else {
            asm volatile("s_waitcnt vmcnt(0)" ::: "memory");
        }
        __builtin_amdgcn_s_barrier();          // chunk kc data ready
        __builtin_amdgcn_sched_barrier(0);

        const float* flc = fl[kc & 1];
#pragma unroll 8
        for (int c = 0; c < 256; ++c) {
            float m = flc[c * 8 + tg];
            float4 wv = WpT4[(long long)(kc * 256 + c) * 32 + dg];
            acc.x += m * wv.x; acc.y += m * wv.y; acc.z += m * wv.z; acc.w += m * wv.w;
        }
        __builtin_amdgcn_s_barrier();          // safe to overwrite fl[kc&1]
    }

    float n2 = acc.x * acc.x + acc.y * acc.y + acc.z * acc.z + acc.w * acc.w;
#pragma unroll
    for (int off = 1; off < 32; off <<= 1) n2 += __shfl_xor(n2, off);
    float scale = 1.0f / fmaxf(sqrtf(n2), 1e-12f);

    long long bt = (long long)b * T + t0 + tg;
    reinterpret_cast<float4*>(xn)[bt * 32 + dg] =
        make_float4(acc.x * scale, acc.y * scale, acc.z * scale, acc.w * scale);
}

// ---------------------------------------------------------------------------
// simfc: banded sims + FC + bias + relu (verified rounds 1-7)
// ---------------------------------------------------------------------------
__global__ __launch_bounds__(128) void simfc_kernel(const float* __restrict__ xn,
                                                    const float* __restrict__ WfT,
                                                    const float* __restrict__ bf,
                                                    float* __restrict__ out) {
    int bt = blockIdx.x;
    int b = bt >> 9, t = bt & 511;
    int tid = threadIdx.x;
    __shared__ __align__(16) float q[D];
    __shared__ float sim[L];
    q[tid] = xn[(long long)bt * D + tid];
    __syncthreads();

    if (tid < L) {
        float acc = 0.f;
        int s = t + tid - HALF;
        if (s >= 0 && s < T) {
            const float4* xr = reinterpret_cast<const float4*>(xn + (((long long)b << 9) + s) * D);
            const float4* q4 = reinterpret_cast<const float4*>(q);
#pragma unroll
            for (int d4 = 0; d4 < D / 4; ++d4) {
                float4 xv = xr[d4];
                float4 qv = q4[d4];
                acc += qv.x * xv.x + qv.y * xv.y + qv.z * xv.z + qv.w * xv.w;
            }
        }
        sim[tid] = acc;
    }
    __syncthreads();

    float acc = bf[tid];
#pragma unroll 4
    for (int l = 0; l < L; ++l) acc += sim[l] * WfT[l * OUTD + tid];
    out[(long long)bt * OUTD + tid] = fmaxf(acc, 0.0f);
}

// ---------------------------------------------------------------------------
extern "C" void kernel_launch(void* const* d_in, const int* in_sizes, int n_in,
                              void* d_out, int out_size, void* d_ws, size_t ws_size,
                              hipStream_t stream) {
    const float* x1 = (const float*)d_in[0];
    const float* x2 = (const float*)d_in[1];
    const float* Wp = (const float*)d_in[2];
    const float* Wf = (const float*)d_in[3];
    const float* bf = (const float*)d_in[4];
    float* out = (float*)d_out;

    float* ws = (float*)d_ws;
    float* WpT   = ws;                   // 2048*128   = 262144 floats
    float* WfT   = WpT + 262144;         // 101*128    = 12928
    float* xn    = WfT + 12928;          // 4*512*128  = 262144
    float* feats = xn + 262144;          // 4*2048*512 = 4194304
    // total ~4.73M floats = 18.9 MB

    hipLaunchKernelGGL(meanprep_kernel, dim3(8499), dim3(256), 0, stream,
                       x1, x2, feats, Wp, Wf, WpT, WfT);
    hipLaunchKernelGGL(projnorm_kernel, dim3(256), dim3(256), 0, stream, feats, WpT, xn);
    hipLaunchKernelGGL(simfc_kernel, dim3(2048), dim3(128), 0, stream, xn, WfT, bf, out);
}